// Round 8
// baseline (601.756 us; speedup 1.0000x reference)
//
#include <hip/hip_runtime.h>
#include <hip/hip_bf16.h>
#include <math.h>

// Problem constants
constexpr int cB = 4, cT = 256, cS = 400, cD = 512, cV = 50000, cNX = 50;
constexpr int cVEXT = cV + cNX;           // 50050
constexpr int cPAN  = (cV + 127) / 128;   // 391 col panels of the big GEMM
constexpr int cCBLD = cVEXT * 2;          // ushort stride of one fp32 out row
constexpr int cMQ   = cB * cT;            // 1024

typedef __attribute__((ext_vector_type(8))) short short8v;   // 8 bf16
typedef __attribute__((ext_vector_type(4))) float floatx4;

__device__ inline ushort f2bf(float f) {
    union { float f; unsigned u; } v; v.f = f;
    unsigned r = (v.u + 0x7FFFu + ((v.u >> 16) & 1u)) >> 16;
    return (ushort)r;
}
__device__ inline float bf2f(ushort u) {
    union { unsigned u; float f; } v; v.u = ((unsigned)u) << 16;
    return v.f;
}

// ---------------------------------------------------------------------------
// fp32 -> bf16 cast
// ---------------------------------------------------------------------------
__global__ __launch_bounds__(256) void cast_kernel(
    const float* __restrict__ src, ushort* __restrict__ dst, int n4)
{
    const int stride = gridDim.x * 256;
    for (int i = blockIdx.x * 256 + threadIdx.x; i < n4; i += stride) {
        float4 v = *(const float4*)(src + (size_t)i * 4);
        ushort4 o;
        o.x = f2bf(v.x); o.y = f2bf(v.y); o.z = f2bf(v.z); o.w = f2bf(v.w);
        *(ushort4*)(dst + (size_t)i * 4) = o;
    }
}

// ---------------------------------------------------------------------------
// bf16 MFMA GEMM v3: 128x128 tile, BK=32, 4 waves (2x2).
// - LDS in FRAGMENT order (pre-permuted global src, linear global_load_lds
//   dest): chunk = 16 rows x 32 k = 1024 B; lane reads base + lane*16 ->
//   bank-conflict-free ds_read_b128.
// - Counted-vmcnt pipeline: raw s_barrier + s_waitcnt vmcnt(4); prefetch of
//   k-step t+1 stays in flight across the barriers of step t.
// - STATS=true: bf16 C via LDS transpose (coalesced ushort4 stores, row
//   stride cbld ushorts) + per-(panel,row) softmax partials, transposed
//   pm[pan*M+row]; XCD-chunked job swizzle. STATS=false: fp32 C + bias.
// ---------------------------------------------------------------------------
template<bool STATS>
__global__ __launch_bounds__(256) void gemm3(
    const ushort* __restrict__ A, const ushort* __restrict__ Wb,
    const float* __restrict__ bias,
    float* __restrict__ Cf, ushort* __restrict__ Cb, int cbld,
    float* __restrict__ pm, float* __restrict__ ps,
    int M, int N, int K, int ldc)
{
    __shared__ ushort As[2][128 * 32];   // 8 chunks x 512 ushorts, frag order
    __shared__ ushort Bs[2][128 * 32];
    __shared__ float sm_m[2][128];
    __shared__ float sm_s[2][128];

    const int tid  = threadIdx.x;
    const int lane = tid & 63;
    const int wv   = tid >> 6;
    const int wm   = wv >> 1;
    const int wn   = wv & 1;

    int bm, bn;
    if constexpr (STATS) {
        // XCD-chunked swizzle: nwg = 8*cPAN, 8 | nwg
        const int wg  = blockIdx.y * gridDim.x + blockIdx.x;
        const int nwg = gridDim.x * gridDim.y;
        const int j   = (wg & 7) * (nwg >> 3) + (wg >> 3);
        bm  = (j & 7) * 128;           // gridDim.x == 8 row-blocks
        bn  = (j >> 3) * 128;
    } else {
        bm = blockIdx.x * 128;
        bn = blockIdx.y * 128;
    }

    const int rA = lane & 15;          // fragment row within chunk
    const int kA = (lane >> 4) * 8;    // fragment k offset
    const int nt = K >> 5;

    floatx4 acc[4][4] = {};

    auto stage = [&](int bidx, int t) {
        const int k0 = t * 32;
        #pragma unroll
        for (int c = 0; c < 2; ++c) {
            const int chunk = wv * 2 + c;
            int ga = bm + chunk * 16 + rA; if (ga >= M) ga = M - 1;
            __builtin_amdgcn_global_load_lds(
                (const __attribute__((address_space(1))) void*)(A + (size_t)ga * K + k0 + kA),
                (__attribute__((address_space(3))) void*)&As[bidx][chunk * 512], 16, 0, 0);
        }
        #pragma unroll
        for (int c = 0; c < 2; ++c) {
            const int chunk = wv * 2 + c;
            int gb = bn + chunk * 16 + rA; if (gb >= N) gb = N - 1;
            __builtin_amdgcn_global_load_lds(
                (const __attribute__((address_space(1))) void*)(Wb + (size_t)gb * K + k0 + kA),
                (__attribute__((address_space(3))) void*)&Bs[bidx][chunk * 512], 16, 0, 0);
        }
    };

    stage(0, 0);
    int buf = 0;

    for (int t = 0; t < nt; ++t) {
        if (t + 1 < nt) {
            stage(buf ^ 1, t + 1);
            asm volatile("s_waitcnt vmcnt(4)" ::: "memory");  // prev 4 landed
        } else {
            asm volatile("s_waitcnt vmcnt(0)" ::: "memory");
        }
        __builtin_amdgcn_s_barrier();                         // buf ready
        asm volatile("" ::: "memory");

        short8v a[4], b[4];
        #pragma unroll
        for (int mi = 0; mi < 4; ++mi)
            a[mi] = *(const short8v*)&As[buf][(wm * 4 + mi) * 512 + lane * 8];
        #pragma unroll
        for (int ni = 0; ni < 4; ++ni)
            b[ni] = *(const short8v*)&Bs[buf][(wn * 4 + ni) * 512 + lane * 8];
        #pragma unroll
        for (int mi = 0; mi < 4; ++mi)
            #pragma unroll
            for (int ni = 0; ni < 4; ++ni)
                acc[mi][ni] = __builtin_amdgcn_mfma_f32_16x16x32_bf16(
                    a[mi], b[ni], acc[mi][ni], 0, 0, 0);

        asm volatile("" ::: "memory");
        __builtin_amdgcn_s_barrier();                         // reads done
        buf ^= 1;
    }

    // ---- epilogue ----
    const int fr = lane & 15;
    const int g  = lane >> 4;

    float bv[4]; bool val[4];
    #pragma unroll
    for (int ni = 0; ni < 4; ++ni) {
        const int colg = bn + wn * 64 + ni * 16 + fr;
        val[ni] = (colg < N);
        bv[ni] = val[ni] ? bias[colg] : 0.f;
    }
    #pragma unroll
    for (int mi = 0; mi < 4; ++mi)
        #pragma unroll
        for (int ni = 0; ni < 4; ++ni)
            #pragma unroll
            for (int r = 0; r < 4; ++r)
                acc[mi][ni][r] += bv[ni];

    if constexpr (STATS) {
        // per-(mi,r) row stats over this wave's 64 cols
        #pragma unroll
        for (int mi = 0; mi < 4; ++mi) {
            #pragma unroll
            for (int r = 0; r < 4; ++r) {
                float mx = -1e30f;
                #pragma unroll
                for (int ni = 0; ni < 4; ++ni)
                    if (val[ni]) mx = fmaxf(mx, acc[mi][ni][r]);
                #pragma unroll
                for (int sw = 1; sw < 16; sw <<= 1)
                    mx = fmaxf(mx, __shfl_xor(mx, sw));
                float sm = 0.f;
                #pragma unroll
                for (int ni = 0; ni < 4; ++ni)
                    if (val[ni]) sm += __expf(acc[mi][ni][r] - mx);
                #pragma unroll
                for (int sw = 1; sw < 16; sw <<= 1)
                    sm += __shfl_xor(sm, sw);
                if (fr == 0) {
                    const int rl = wm * 64 + mi * 16 + g * 4 + r;
                    sm_m[wn][rl] = mx;
                    sm_s[wn][rl] = sm;
                }
            }
        }
        __syncthreads();
        if (tid < 128) {
            const float m0 = sm_m[0][tid], m1 = sm_m[1][tid];
            const float s0 = sm_s[0][tid], s1 = sm_s[1][tid];
            const float mm = fmaxf(m0, m1);
            const float ss = s0 * __expf(m0 - mm) + s1 * __expf(m1 - mm);
            const int grow = bm + tid;
            if (grow < M) {
                pm[(size_t)gridDim.y * 0 + (size_t)( (bn >> 7) ) * M + grow] = mm;
                ps[(size_t)( (bn >> 7) ) * M + grow] = ss;
            }
        }

        // coalesced bf16 C store via LDS transpose (272 B padded rows)
        ushort* eps = (ushort*)As;     // 8192 ushorts available
        constexpr int LDW = 136;       // ushorts per row
        #pragma unroll 1
        for (int mi = 0; mi < 4; ++mi) {
            __syncthreads();
            #pragma unroll
            for (int ni = 0; ni < 4; ++ni)
                #pragma unroll
                for (int r = 0; r < 4; ++r)
                    eps[(wm * 16 + g * 4 + r) * LDW + wn * 64 + ni * 16 + fr] =
                        f2bf(acc[mi][ni][r]);
            __syncthreads();
            #pragma unroll
            for (int p = 0; p < 2; ++p) {
                const int idx = p * 256 + tid;      // 0..511
                const int lr  = idx >> 4;           // 0..31
                const int seg = idx & 15;           // 0..15
                const int colg = bn + seg * 8;
                if (colg + 8 <= N) {
                    const int grow = bm + (lr >> 4) * 64 + mi * 16 + (lr & 15);
                    if (grow < M) {
                        ushort4 v0 = *(const ushort4*)&eps[lr * LDW + seg * 8];
                        ushort4 v1 = *(const ushort4*)&eps[lr * LDW + seg * 8 + 4];
                        ushort* dp = Cb + (size_t)grow * cbld + colg;
                        *(ushort4*)dp = v0;
                        *(ushort4*)(dp + 4) = v1;
                    }
                }
            }
        }
    } else {
        #pragma unroll
        for (int mi = 0; mi < 4; ++mi) {
            #pragma unroll
            for (int ni = 0; ni < 4; ++ni) {
                if (!val[ni]) continue;
                const int colg = bn + wn * 64 + ni * 16 + fr;
                #pragma unroll
                for (int r = 0; r < 4; ++r) {
                    const int row = bm + wm * 64 + mi * 16 + g * 4 + r;
                    if (row < M) Cf[(size_t)row * ldc + colg] = acc[mi][ni][r];
                }
            }
        }
    }
}

// ---------------------------------------------------------------------------
// combine partials (transposed pm/ps) -> rowadd = log(pgen) - m - log(s).
// 16 blocks x 256 thr; block = 64 rows, 4 panel-stripes; lane reads 64
// CONSECUTIVE rows per panel (coalesced); stripes merged via LDS.
// ---------------------------------------------------------------------------
__global__ __launch_bounds__(256) void combine_kernel(
    const float* __restrict__ pm, const float* __restrict__ ps,
    const float* __restrict__ pgen, float* __restrict__ rowadd)
{
    const int lane = threadIdx.x & 63;
    const int wv   = threadIdx.x >> 6;    // panel stripe 0..3
    const int row  = blockIdx.x * 64 + lane;

    float m = -1e30f, s = 0.f;
    #pragma unroll 2
    for (int i = wv; i < cPAN; i += 4) {
        const float mi = pm[(size_t)i * cMQ + row];
        const float si = ps[(size_t)i * cMQ + row];
        const float nm = fmaxf(m, mi);
        s = s * __expf(m - nm) + si * __expf(mi - nm);
        m = nm;
    }
    __shared__ float rm[4][64], rs[4][64];
    rm[wv][lane] = m; rs[wv][lane] = s;
    __syncthreads();
    if (wv == 0) {
        m = rm[0][lane]; s = rs[0][lane];
        #pragma unroll
        for (int i = 1; i < 4; ++i) {
            const float m2 = rm[i][lane], s2 = rs[i][lane];
            const float nm = fmaxf(m, m2);
            s = s * __expf(m - nm) + s2 * __expf(m2 - nm);
            m = nm;
        }
        rowadd[row] = __logf(pgen[row]) - m - __logf(s);
    }
}

// ---------------------------------------------------------------------------
// Flat disjoint transform (big-ws path)
// ---------------------------------------------------------------------------
__global__ __launch_bounds__(512) void transform_flat(
    float* __restrict__ out, const ushort* __restrict__ lb,
    const float* __restrict__ rowadd)
{
    const int row = blockIdx.y;
    const float a = rowadd[row];
    constexpr float LOGMIN = -20.72326583694641f;   // log(1e-9)
    const ushort* src = lb + (size_t)row * cV;
    float* dst = out + (size_t)row * cVEXT;
    constexpr int NI = cV / 8;   // 6250
    for (int i = blockIdx.x * 512 + threadIdx.x; i <= NI; i += gridDim.x * 512) {
        if (i < NI) {
            const short8v sv = *(const short8v*)(src + (size_t)i * 8);
            const int v = i * 8;
            #pragma unroll
            for (int j = 0; j < 4; ++j) {
                float2 o;
                o.x = fmaxf(bf2f((ushort)sv[2 * j])     + a, LOGMIN);
                o.y = fmaxf(bf2f((ushort)sv[2 * j + 1]) + a, LOGMIN);
                *(float2*)&dst[v + 2 * j] = o;
            }
        } else {
            #pragma unroll
            for (int v = cV; v < cVEXT; v += 2) {
                float2 o; o.x = LOGMIN; o.y = LOGMIN;
                *(float2*)&dst[v] = o;
            }
        }
    }
}

// ---------------------------------------------------------------------------
// scatter fixup: out[row,p] = log(max(exp(out[row,p])+sum, 1e-9))
// ---------------------------------------------------------------------------
__global__ __launch_bounds__(256) void fixup_kernel(
    float* __restrict__ out, const int* __restrict__ ebev,
    const float* __restrict__ attn)
{
    const int row = blockIdx.x;
    const int b = row / cT;
    const int tid = threadIdx.x;
    __shared__ int   pos[cS];
    __shared__ float add[cS];
    for (int s = tid; s < cS; s += 256) {
        pos[s] = ebev[b * cS + s];
        add[s] = attn[(size_t)row * cS + s];
    }
    __syncthreads();
    float* rowf = out + (size_t)row * cVEXT;
    for (int s = tid; s < cS; s += 256) {
        const int p = pos[s];
        bool leader = true;
        for (int s2 = 0; s2 < s; ++s2)
            if (pos[s2] == p) { leader = false; break; }
        if (!leader) continue;
        float sum = add[s];
        for (int s2 = s + 1; s2 < cS; ++s2)
            if (pos[s2] == p) sum += add[s2];
        const float base = __expf(rowf[p]);
        rowf[p] = __logf(fmaxf(base + sum, 1e-9f));
    }
}

// ---------------------------------------------------------------------------
// Fallback (small ws): segmented in-place expand + fixup (r6 proven)
// ---------------------------------------------------------------------------
__global__ __launch_bounds__(512) void transform_inplace(
    float* __restrict__ out, const float* __restrict__ rowadd,
    const int* __restrict__ ebev, const float* __restrict__ attn)
{
    const int row = blockIdx.x;
    const int b   = row / cT;
    const int tid = threadIdx.x;
    constexpr float LOGMIN = -20.72326583694641f;

    __shared__ int   pos[cS];
    __shared__ float add[cS];
    for (int s = tid; s < cS; s += 512) {
        pos[s] = ebev[b * cS + s];
        add[s] = attn[(size_t)row * cS + s];
    }

    const float a = rowadd[row];
    ushort* rowu = (ushort*)out + (size_t)row * cCBLD;
    float*  rowf = out + (size_t)row * cVEXT;

    #pragma unroll 1
    for (int L = 32768; L >= 2; L >>= 1) {
        const int hi = (2 * L < cVEXT) ? 2 * L : cVEXT;
        for (int i = L + 2 * tid; i < hi; i += 1024) {
            const float x0 = bf2f(rowu[i]);
            const float x1 = bf2f(rowu[i + 1]);
            float2 o;
            o.x = (i     < cV) ? fmaxf(x0 + a, LOGMIN) : LOGMIN;
            o.y = (i + 1 < cV) ? fmaxf(x1 + a, LOGMIN) : LOGMIN;
            *(float2*)&rowf[i] = o;
        }
        __syncthreads();
    }
    if (tid == 0) {
        const float x1 = bf2f(rowu[1]);
        const float x0 = bf2f(rowu[0]);
        rowf[1] = fmaxf(x1 + a, LOGMIN);
        rowf[0] = fmaxf(x0 + a, LOGMIN);
    }
    __syncthreads();

    for (int s = tid; s < cS; s += 512) {
        const int p = pos[s];
        bool leader = true;
        for (int s2 = 0; s2 < s; ++s2)
            if (pos[s2] == p) { leader = false; break; }
        if (!leader) continue;
        float sum = add[s];
        for (int s2 = s + 1; s2 < cS; ++s2)
            if (pos[s2] == p) sum += add[s2];
        const float base = __expf(rowf[p]);
        rowf[p] = __logf(fmaxf(base + sum, 1e-9f));
    }
}

// ---------------------------------------------------------------------------
// p_gen = sigmoid(x . pgen_w + pgen_b)
// ---------------------------------------------------------------------------
__global__ __launch_bounds__(64) void pgen_kernel(
    const float* __restrict__ x, const float* __restrict__ w,
    const float* __restrict__ b, float* __restrict__ pgen)
{
    const int row = blockIdx.x;
    const int lane = threadIdx.x;
    const float* xr = x + (size_t)row * cD;
    float s = 0.f;
    for (int i = lane; i < cD; i += 64) s += xr[i] * w[i];
    #pragma unroll
    for (int off = 32; off; off >>= 1) s += __shfl_down(s, off);
    if (lane == 0) pgen[row] = 1.f / (1.f + __expf(-(s + b[0])));
}

// ---------------------------------------------------------------------------
// attention distribution (scaled by 1-pgen)
// ---------------------------------------------------------------------------
__global__ __launch_bounds__(256) void attn_kernel(
    const float* __restrict__ q, const float* __restrict__ k,
    const int* __restrict__ src_mask, const float* __restrict__ pgen,
    float* __restrict__ attn)
{
    constexpr float scale = 0.04419417382415922f;  // 1/sqrt(512)
    const int row = blockIdx.x;      // b*T + t
    const int b = row / cT;
    const int tid = threadIdx.x;

    __shared__ __align__(16) float qs[cD];
    __shared__ float sc[cS];
    __shared__ float red[4];

    for (int i = tid; i < cD; i += 256) qs[i] = q[(size_t)row * cD + i];
    __syncthreads();

    for (int s = tid; s < cS; s += 256) {
        const float* kr = k + ((size_t)b * cS + s) * cD;
        float dot = 0.f;
        #pragma unroll 4
        for (int i = 0; i < cD; i += 4) {
            float4 kv = *(const float4*)(kr + i);
            float4 qv = *(const float4*)(qs + i);
            dot += qv.x * kv.x + qv.y * kv.y + qv.z * kv.z + qv.w * kv.w;
        }
        float v = dot * scale;
        if (src_mask[b * cS + s] == 0) v = -1e9f;
        sc[s] = v;
    }
    __syncthreads();

    float m = -3.4e38f;
    for (int s = tid; s < cS; s += 256) m = fmaxf(m, sc[s]);
    #pragma unroll
    for (int off = 32; off; off >>= 1) m = fmaxf(m, __shfl_down(m, off));
    if ((tid & 63) == 0) red[tid >> 6] = m;
    __syncthreads();
    m = fmaxf(fmaxf(red[0], red[1]), fmaxf(red[2], red[3]));
    __syncthreads();

    float sum = 0.f;
    for (int s = tid; s < cS; s += 256) {
        float e = __expf(sc[s] - m);
        sc[s] = e;
        sum += e;
    }
    #pragma unroll
    for (int off = 32; off; off >>= 1) sum += __shfl_down(sum, off);
    if ((tid & 63) == 0) red[tid >> 6] = sum;
    __syncthreads();
    sum = red[0] + red[1] + red[2] + red[3];

    const float w = (1.f - pgen[row]) / sum;
    for (int s = tid; s < cS; s += 256)
        attn[(size_t)row * cS + s] = sc[s] * w;
}

extern "C" void kernel_launch(void* const* d_in, const int* in_sizes, int n_in,
                              void* d_out, int out_size, void* d_ws, size_t ws_size,
                              hipStream_t stream)
{
    const float* x      = (const float*)d_in[0];   // (B,T,D)
    const float* enc    = (const float*)d_in[1];   // (B,S,D)
    const int*   mask   = (const int*)d_in[2];     // (B,1,S)
    const int*   ebev   = (const int*)d_in[3];     // (B,S)
    const float* fc_w   = (const float*)d_in[5];   // (V,D)
    const float* fc_b   = (const float*)d_in[6];   // (V,)
    const float* pgen_w = (const float*)d_in[7];   // (1,D)
    const float* pgen_b = (const float*)d_in[8];   // (1,)
    const float* wq     = (const float*)d_in[9];   // (D,D)
    const float* bq     = (const float*)d_in[10];  // (D,)
    const float* wk     = (const float*)d_in[11];  // (D,D)
    const float* bk     = (const float*)d_in[12];  // (D,)
    float* out = (float*)d_out;

    // workspace layout
    float* ws     = (float*)d_ws;
    float* q      = ws;                                   // 1024*512
    float* kbuf   = q + (size_t)cB * cT * cD;             // 1600*512
    float* pgen   = kbuf + (size_t)cB * cS * cD;          // 1024
    float* attn   = pgen + cB * cT;                       // 1024*400
    float* pm     = attn + (size_t)cB * cT * cS;          // 391*1024 (transposed)
    float* ps     = pm + (size_t)cPAN * cMQ;              // 391*1024
    float* rowadd = ps + (size_t)cPAN * cMQ;              // 1024
    ushort* xb    = (ushort*)(rowadd + cMQ);
    ushort* encb  = xb + (size_t)cB * cT * cD;
    ushort* wqb   = encb + (size_t)cB * cS * cD;
    ushort* wkb   = wqb + (size_t)cD * cD;
    ushort* tail  = wkb + (size_t)cD * cD;   // big: logits buf; small: wb

    const size_t base_bytes = (size_t)((char*)tail - (char*)d_ws);
    const bool big = ws_size >= base_bytes + (size_t)cMQ * cV * 2 + 1024;

    const dim3 blk(256);
    const int MQ = cMQ;        // 1024
    const int MK = cB * cS;    // 1600

    ushort* wb;        // bf16 W
    ushort* logitsb;   // bf16 logits (big path)
    int     cbld;
    if (big) {
        wb = (ushort*)d_out;   // W lives in d_out until transform consumes it
        logitsb = tail;
        cbld = cV;
    } else {
        wb = tail;
        logitsb = (ushort*)d_out;  // in-slot
        cbld = cCBLD;
    }

    // casts
    cast_kernel<<<dim3(512), blk, 0, stream>>>(x, xb, (cB * cT * cD) / 4);
    cast_kernel<<<dim3(512), blk, 0, stream>>>(enc, encb, (cB * cS * cD) / 4);
    cast_kernel<<<dim3(256), blk, 0, stream>>>(wq, wqb, (cD * cD) / 4);
    cast_kernel<<<dim3(256), blk, 0, stream>>>(wk, wkb, (cD * cD) / 4);
    cast_kernel<<<dim3(2048), blk, 0, stream>>>(fc_w, wb, (cV * cD) / 4);

    // projections (bf16 MFMA, fp32 out)
    gemm3<false><<<dim3(MQ / 128, cD / 128), blk, 0, stream>>>(
        xb, wqb, bq, q, nullptr, 0, nullptr, nullptr, MQ, cD, cD, cD);
    gemm3<false><<<dim3((MK + 127) / 128, cD / 128), blk, 0, stream>>>(
        encb, wkb, bk, kbuf, nullptr, 0, nullptr, nullptr, MK, cD, cD, cD);
    pgen_kernel<<<dim3(MQ), dim3(64), 0, stream>>>(x, pgen_w, pgen_b, pgen);

    // attention distribution
    attn_kernel<<<dim3(MQ), blk, 0, stream>>>(q, kbuf, mask, pgen, attn);

    // big logits GEMM: bf16 C + softmax partials (transposed)
    gemm3<true><<<dim3(8, cPAN), blk, 0, stream>>>(
        xb, wb, fc_b, nullptr, logitsb, cbld, pm, ps, MQ, cV, cD, 0);

    // combine partials -> rowadd (coalesced)
    combine_kernel<<<dim3(MQ / 64), blk, 0, stream>>>(pm, ps, pgen, rowadd);

    if (big) {
        transform_flat<<<dim3(13, MQ), dim3(512), 0, stream>>>(out, logitsb, rowadd);
        fixup_kernel<<<dim3(MQ), blk, 0, stream>>>(out, ebev, attn);
    } else {
        transform_inplace<<<dim3(MQ), dim3(512), 0, stream>>>(out, rowadd, ebev, attn);
    }
}

// Round 9
// 449.890 us; speedup vs baseline: 1.3376x; 1.3376x over previous
//
#include <hip/hip_runtime.h>
#include <hip/hip_bf16.h>
#include <math.h>

// Problem constants
constexpr int cB = 4, cT = 256, cS = 400, cD = 512, cV = 50000, cNX = 50;
constexpr int cVEXT = cV + cNX;           // 50050
constexpr int cPAN  = (cV + 127) / 128;   // 391 col panels of the big GEMM
constexpr int cMQ   = cB * cT;            // 1024

typedef __attribute__((ext_vector_type(8))) short short8v;   // 8 bf16
typedef __attribute__((ext_vector_type(4))) float floatx4;

__device__ inline ushort f2bf(float f) {
    union { float f; unsigned u; } v; v.f = f;
    unsigned r = (v.u + 0x7FFFu + ((v.u >> 16) & 1u)) >> 16;
    return (ushort)r;
}

// ---------------------------------------------------------------------------
// fp32 -> bf16 cast
// ---------------------------------------------------------------------------
__global__ __launch_bounds__(256) void cast_kernel(
    const float* __restrict__ src, ushort* __restrict__ dst, int n4)
{
    const int stride = gridDim.x * 256;
    for (int i = blockIdx.x * 256 + threadIdx.x; i < n4; i += stride) {
        float4 v = *(const float4*)(src + (size_t)i * 4);
        ushort4 o;
        o.x = f2bf(v.x); o.y = f2bf(v.y); o.z = f2bf(v.z); o.w = f2bf(v.w);
        *(ushort4*)(dst + (size_t)i * 4) = o;
    }
}

// ---------------------------------------------------------------------------
// bf16 MFMA GEMM (r7-benched structure: 144us on the big shape).
// 128x128 tile, BK=32, 4 waves (2x2), A+B double-buffered, one __syncthreads
// per K-step, stage(t+1) issued before compute(t).
// STATS=true: XCD-chunked job swizzle (grid x=8 row-blocks, y=391 panels);
//   writes fp32 C (+bias) at stride ldc AND per-(panel,row) softmax partials
//   pm/ps in transposed layout pm[pan*M + row].
// STATS=false: plain mapping, fp32 C + bias.
// ---------------------------------------------------------------------------
template<bool STATS>
__global__ __launch_bounds__(256) void gemm2(
    const ushort* __restrict__ A, const ushort* __restrict__ Wb,
    const float* __restrict__ bias, float* __restrict__ Cf,
    float* __restrict__ pm, float* __restrict__ ps,
    int M, int N, int K, int ldc)
{
    __shared__ ushort As[2][128 * 32];
    __shared__ ushort Bs[2][128 * 32];
    __shared__ float sm_m[2][128];
    __shared__ float sm_s[2][128];

    const int tid  = threadIdx.x;
    const int lane = tid & 63;
    const int wv   = tid >> 6;
    const int wm   = wv >> 1;
    const int wn   = wv & 1;

    int bm, bn, pan = 0;
    if constexpr (STATS) {
        // XCD-chunked swizzle: nwg = 8*cPAN, 8 | nwg
        const int wg  = blockIdx.y * gridDim.x + blockIdx.x;
        const int nwg = gridDim.x * gridDim.y;
        const int j   = (wg & 7) * (nwg >> 3) + (wg >> 3);
        pan = j >> 3;                  // gridDim.x == 8 row-blocks
        bm  = (j & 7) * 128;
        bn  = pan * 128;
    } else {
        bm = blockIdx.x * 128;
        bn = blockIdx.y * 128;
    }

    const int srow = lane >> 2;        // 0..15
    const int sk   = (lane & 3) * 8;   // bf16 elems

    const int nt = K >> 5;

    floatx4 acc[4][4] = {};

    auto stage = [&](int bidx, int t) {
        const int k0 = t * 32;
        #pragma unroll
        for (int c = 0; c < 2; ++c) {
            const int lr = wv * 32 + c * 16;
            int ga = bm + lr + srow; if (ga >= M) ga = M - 1;
            __builtin_amdgcn_global_load_lds(
                (const __attribute__((address_space(1))) void*)(A + (size_t)ga * K + k0 + sk),
                (__attribute__((address_space(3))) void*)&As[bidx][lr * 32], 16, 0, 0);
        }
        #pragma unroll
        for (int c = 0; c < 2; ++c) {
            const int lr = wv * 32 + c * 16;
            int gb = bn + lr + srow; if (gb >= N) gb = N - 1;
            __builtin_amdgcn_global_load_lds(
                (const __attribute__((address_space(1))) void*)(Wb + (size_t)gb * K + k0 + sk),
                (__attribute__((address_space(3))) void*)&Bs[bidx][lr * 32], 16, 0, 0);
        }
    };

    stage(0, 0);
    __syncthreads();

    const int fr = lane & 15;
    const int g  = lane >> 4;
    int buf = 0;

    for (int t = 0; t < nt; ++t) {
        if (t + 1 < nt) stage(buf ^ 1, t + 1);
        short8v a[4], b[4];
        #pragma unroll
        for (int mi = 0; mi < 4; ++mi)
            a[mi] = *(const short8v*)&As[buf][(wm * 64 + mi * 16 + fr) * 32 + g * 8];
        #pragma unroll
        for (int ni = 0; ni < 4; ++ni)
            b[ni] = *(const short8v*)&Bs[buf][(wn * 64 + ni * 16 + fr) * 32 + g * 8];
        #pragma unroll
        for (int mi = 0; mi < 4; ++mi)
            #pragma unroll
            for (int ni = 0; ni < 4; ++ni)
                acc[mi][ni] = __builtin_amdgcn_mfma_f32_16x16x32_bf16(
                    a[mi], b[ni], acc[mi][ni], 0, 0, 0);
        __syncthreads();
        buf ^= 1;
    }

    // ---- epilogue ----
    float bv[4]; bool val[4];
    #pragma unroll
    for (int ni = 0; ni < 4; ++ni) {
        const int colg = bn + wn * 64 + ni * 16 + fr;
        val[ni] = (colg < N);
        bv[ni] = val[ni] ? bias[colg] : 0.f;
    }
    #pragma unroll
    for (int mi = 0; mi < 4; ++mi)
        #pragma unroll
        for (int ni = 0; ni < 4; ++ni)
            #pragma unroll
            for (int r = 0; r < 4; ++r)
                acc[mi][ni][r] += bv[ni];

    if constexpr (STATS) {
        // per-(mi,r) row stats over this wave's 64 cols
        #pragma unroll
        for (int mi = 0; mi < 4; ++mi) {
            #pragma unroll
            for (int r = 0; r < 4; ++r) {
                float mx = -1e30f;
                #pragma unroll
                for (int ni = 0; ni < 4; ++ni)
                    if (val[ni]) mx = fmaxf(mx, acc[mi][ni][r]);
                #pragma unroll
                for (int sw = 1; sw < 16; sw <<= 1)
                    mx = fmaxf(mx, __shfl_xor(mx, sw));
                float sm = 0.f;
                #pragma unroll
                for (int ni = 0; ni < 4; ++ni)
                    if (val[ni]) sm += __expf(acc[mi][ni][r] - mx);
                #pragma unroll
                for (int sw = 1; sw < 16; sw <<= 1)
                    sm += __shfl_xor(sm, sw);
                if (fr == 0) {
                    const int rl = wm * 64 + mi * 16 + g * 4 + r;
                    sm_m[wn][rl] = mx;
                    sm_s[wn][rl] = sm;
                }
            }
        }
        __syncthreads();
        if (tid < 128) {
            const float m0 = sm_m[0][tid], m1 = sm_m[1][tid];
            const float s0 = sm_s[0][tid], s1 = sm_s[1][tid];
            const float mm = fmaxf(m0, m1);
            const float ss = s0 * __expf(m0 - mm) + s1 * __expf(m1 - mm);
            const int grow = bm + tid;
            if (grow < M) {
                pm[(size_t)pan * M + grow] = mm;   // transposed: contiguous
                ps[(size_t)pan * M + grow] = ss;
            }
        }
    }

    // fp32 C store (+bias already applied); 16 lanes x 4B = 64B per row seg
    #pragma unroll
    for (int mi = 0; mi < 4; ++mi) {
        #pragma unroll
        for (int ni = 0; ni < 4; ++ni) {
            if (!val[ni]) continue;
            const int colg = bn + wn * 64 + ni * 16 + fr;
            #pragma unroll
            for (int r = 0; r < 4; ++r) {
                const int row = bm + wm * 64 + mi * 16 + g * 4 + r;
                if (row < M) Cf[(size_t)row * ldc + colg] = acc[mi][ni][r];
            }
        }
    }
}

// ---------------------------------------------------------------------------
// combine partials (transposed pm/ps) -> rowadd = log(pgen) - m - log(s).
// Block = 64 rows x 4 panel-stripes; lanes read 64 consecutive rows per
// panel (coalesced); stripes merged via LDS. (r8-proven correct.)
// ---------------------------------------------------------------------------
__global__ __launch_bounds__(256) void combine_kernel(
    const float* __restrict__ pm, const float* __restrict__ ps,
    const float* __restrict__ pgen, float* __restrict__ rowadd)
{
    const int lane = threadIdx.x & 63;
    const int wv   = threadIdx.x >> 6;    // panel stripe 0..3
    const int row  = blockIdx.x * 64 + lane;

    float m = -1e30f, s = 0.f;
    #pragma unroll 2
    for (int i = wv; i < cPAN; i += 4) {
        const float mi = pm[(size_t)i * cMQ + row];
        const float si = ps[(size_t)i * cMQ + row];
        const float nm = fmaxf(m, mi);
        s = s * __expf(m - nm) + si * __expf(mi - nm);
        m = nm;
    }
    __shared__ float rm[4][64], rs[4][64];
    rm[wv][lane] = m; rs[wv][lane] = s;
    __syncthreads();
    if (wv == 0) {
        m = rm[0][lane]; s = rs[0][lane];
        #pragma unroll
        for (int i = 1; i < 4; ++i) {
            const float m2 = rm[i][lane], s2 = rs[i][lane];
            const float nm = fmaxf(m, m2);
            s = s * __expf(m - nm) + s2 * __expf(m2 - nm);
            m = nm;
        }
        rowadd[row] = __logf(pgen[row]) - m - __logf(s);
    }
}

// ---------------------------------------------------------------------------
// Per-row fp32 in-place transform + fused scatter fixup. One block per row.
// out[row,v<V] = max(logit + a, LOGMIN); tail = LOGMIN. Fully parallel
// (fp32->fp32 same-address, each element read+written by one thread).
// Then leaders rewrite scatter positions: log(max(exp(l) + sum, 1e-9)).
// ---------------------------------------------------------------------------
__global__ __launch_bounds__(512) void transform_row(
    float* __restrict__ out, const float* __restrict__ rowadd,
    const int* __restrict__ ebev, const float* __restrict__ attn)
{
    const int row = blockIdx.x;
    const int b   = row / cT;
    const int tid = threadIdx.x;
    constexpr float LOGMIN = -20.72326583694641f;   // log(1e-9)

    __shared__ int   pos[cS];
    __shared__ float add[cS];
    for (int s = tid; s < cS; s += 512) {
        pos[s] = ebev[b * cS + s];
        add[s] = attn[(size_t)row * cS + s];
    }

    const float a = rowadd[row];
    float2* rp = (float2*)(out + (size_t)row * cVEXT);   // rows 8B-aligned
    constexpr int NF2 = cVEXT / 2;    // 25025
    constexpr int NV2 = cV / 2;       // 25000
    for (int i = tid; i < NF2; i += 512) {
        float2 o;
        if (i < NV2) {
            float2 v = rp[i];
            o.x = fmaxf(v.x + a, LOGMIN);
            o.y = fmaxf(v.y + a, LOGMIN);
        } else {
            o.x = LOGMIN; o.y = LOGMIN;
        }
        rp[i] = o;
    }
    __syncthreads();

    // scatter fixup
    float* rowf = out + (size_t)row * cVEXT;
    for (int s = tid; s < cS; s += 512) {
        const int p = pos[s];
        bool leader = true;
        for (int s2 = 0; s2 < s; ++s2)
            if (pos[s2] == p) { leader = false; break; }
        if (!leader) continue;
        float sum = add[s];
        for (int s2 = s + 1; s2 < cS; ++s2)
            if (pos[s2] == p) sum += add[s2];
        const float base = __expf(rowf[p]);   // clamped; error << threshold
        rowf[p] = __logf(fmaxf(base + sum, 1e-9f));
    }
}

// ---------------------------------------------------------------------------
// p_gen = sigmoid(x . pgen_w + pgen_b)
// ---------------------------------------------------------------------------
__global__ __launch_bounds__(64) void pgen_kernel(
    const float* __restrict__ x, const float* __restrict__ w,
    const float* __restrict__ b, float* __restrict__ pgen)
{
    const int row = blockIdx.x;
    const int lane = threadIdx.x;
    const float* xr = x + (size_t)row * cD;
    float s = 0.f;
    for (int i = lane; i < cD; i += 64) s += xr[i] * w[i];
    #pragma unroll
    for (int off = 32; off; off >>= 1) s += __shfl_down(s, off);
    if (lane == 0) pgen[row] = 1.f / (1.f + __expf(-(s + b[0])));
}

// ---------------------------------------------------------------------------
// attention distribution (scaled by 1-pgen)
// ---------------------------------------------------------------------------
__global__ __launch_bounds__(256) void attn_kernel(
    const float* __restrict__ q, const float* __restrict__ k,
    const int* __restrict__ src_mask, const float* __restrict__ pgen,
    float* __restrict__ attn)
{
    constexpr float scale = 0.04419417382415922f;  // 1/sqrt(512)
    const int row = blockIdx.x;      // b*T + t
    const int b = row / cT;
    const int tid = threadIdx.x;

    __shared__ __align__(16) float qs[cD];
    __shared__ float sc[cS];
    __shared__ float red[4];

    for (int i = tid; i < cD; i += 256) qs[i] = q[(size_t)row * cD + i];
    __syncthreads();

    for (int s = tid; s < cS; s += 256) {
        const float* kr = k + ((size_t)b * cS + s) * cD;
        float dot = 0.f;
        #pragma unroll 4
        for (int i = 0; i < cD; i += 4) {
            float4 kv = *(const float4*)(kr + i);
            float4 qv = *(const float4*)(qs + i);
            dot += qv.x * kv.x + qv.y * kv.y + qv.z * kv.z + qv.w * kv.w;
        }
        float v = dot * scale;
        if (src_mask[b * cS + s] == 0) v = -1e9f;
        sc[s] = v;
    }
    __syncthreads();

    float m = -3.4e38f;
    for (int s = tid; s < cS; s += 256) m = fmaxf(m, sc[s]);
    #pragma unroll
    for (int off = 32; off; off >>= 1) m = fmaxf(m, __shfl_down(m, off));
    if ((tid & 63) == 0) red[tid >> 6] = m;
    __syncthreads();
    m = fmaxf(fmaxf(red[0], red[1]), fmaxf(red[2], red[3]));
    __syncthreads();

    float sum = 0.f;
    for (int s = tid; s < cS; s += 256) {
        float e = __expf(sc[s] - m);
        sc[s] = e;
        sum += e;
    }
    #pragma unroll
    for (int off = 32; off; off >>= 1) sum += __shfl_down(sum, off);
    if ((tid & 63) == 0) red[tid >> 6] = sum;
    __syncthreads();
    sum = red[0] + red[1] + red[2] + red[3];

    const float w = (1.f - pgen[row]) / sum;
    for (int s = tid; s < cS; s += 256)
        attn[(size_t)row * cS + s] = sc[s] * w;
}

extern "C" void kernel_launch(void* const* d_in, const int* in_sizes, int n_in,
                              void* d_out, int out_size, void* d_ws, size_t ws_size,
                              hipStream_t stream)
{
    const float* x      = (const float*)d_in[0];   // (B,T,D)
    const float* enc    = (const float*)d_in[1];   // (B,S,D)
    const int*   mask   = (const int*)d_in[2];     // (B,1,S)
    const int*   ebev   = (const int*)d_in[3];     // (B,S)
    const float* fc_w   = (const float*)d_in[5];   // (V,D)
    const float* fc_b   = (const float*)d_in[6];   // (V,)
    const float* pgen_w = (const float*)d_in[7];   // (1,D)
    const float* pgen_b = (const float*)d_in[8];   // (1,)
    const float* wq     = (const float*)d_in[9];   // (D,D)
    const float* bq     = (const float*)d_in[10];  // (D,)
    const float* wk     = (const float*)d_in[11];  // (D,D)
    const float* bk     = (const float*)d_in[12];  // (D,)
    float* out = (float*)d_out;

    // workspace layout (~65 MB total; proven to fit in prior rounds)
    float* ws     = (float*)d_ws;
    float* q      = ws;                                   // 1024*512
    float* kbuf   = q + (size_t)cB * cT * cD;             // 1600*512
    float* pgen   = kbuf + (size_t)cB * cS * cD;          // 1024
    float* attn   = pgen + cB * cT;                       // 1024*400
    float* pm     = attn + (size_t)cB * cT * cS;          // 391*1024 (transposed)
    float* ps     = pm + (size_t)cPAN * cMQ;              // 391*1024
    float* rowadd = ps + (size_t)cPAN * cMQ;              // 1024
    ushort* xb    = (ushort*)(rowadd + cMQ);
    ushort* encb  = xb + (size_t)cB * cT * cD;
    ushort* wqb   = encb + (size_t)cB * cS * cD;
    ushort* wkb   = wqb + (size_t)cD * cD;
    ushort* wb    = wkb + (size_t)cD * cD;                // V*D bf16 (51 MB)

    const dim3 blk(256);
    const int MQ = cMQ;        // 1024
    const int MK = cB * cS;    // 1600

    // casts
    cast_kernel<<<dim3(512), blk, 0, stream>>>(x, xb, (cB * cT * cD) / 4);
    cast_kernel<<<dim3(512), blk, 0, stream>>>(enc, encb, (cB * cS * cD) / 4);
    cast_kernel<<<dim3(256), blk, 0, stream>>>(wq, wqb, (cD * cD) / 4);
    cast_kernel<<<dim3(256), blk, 0, stream>>>(wk, wkb, (cD * cD) / 4);
    cast_kernel<<<dim3(2048), blk, 0, stream>>>(fc_w, wb, (cV * cD) / 4);

    // projections (bf16 MFMA, fp32 out)
    gemm2<false><<<dim3(MQ / 128, cD / 128), blk, 0, stream>>>(
        xb, wqb, bq, q, nullptr, nullptr, MQ, cD, cD, cD);
    gemm2<false><<<dim3((MK + 127) / 128, cD / 128), blk, 0, stream>>>(
        encb, wkb, bk, kbuf, nullptr, nullptr, MK, cD, cD, cD);
    pgen_kernel<<<dim3(MQ), dim3(64), 0, stream>>>(x, pgen_w, pgen_b, pgen);

    // attention distribution
    attn_kernel<<<dim3(MQ), blk, 0, stream>>>(q, kbuf, mask, pgen, attn);

    // big logits GEMM: fp32 logits (+bias) into d_out + softmax partials
    gemm2<true><<<dim3(8, cPAN), blk, 0, stream>>>(
        xb, wb, fc_b, out, pm, ps, MQ, cV, cD, cVEXT);

    // combine partials -> rowadd
    combine_kernel<<<dim3(MQ / 64), blk, 0, stream>>>(pm, ps, pgen, rowadd);

    // per-row in-place transform + fused scatter fixup
    transform_row<<<dim3(MQ), dim3(512), 0, stream>>>(out, rowadd, ebev, attn);
}

// Round 10
// 443.479 us; speedup vs baseline: 1.3569x; 1.0145x over previous
//
#include <hip/hip_runtime.h>
#include <hip/hip_bf16.h>
#include <math.h>

// Problem constants
constexpr int cB = 4, cT = 256, cS = 400, cD = 512, cV = 50000, cNX = 50;
constexpr int cVEXT = cV + cNX;           // 50050
constexpr int cPAN  = (cV + 127) / 128;   // 391 col panels of the big GEMM
constexpr int cCBLD = cVEXT * 2;          // ushort stride of one fp32 out row
constexpr int cTOP  = 50100;              // ushort offset of bf16 logits in-slot (byte 100200)
constexpr int cMQ   = cB * cT;            // 1024

typedef __attribute__((ext_vector_type(8))) short short8v;   // 8 bf16
typedef __attribute__((ext_vector_type(4))) float floatx4;

__device__ inline ushort f2bf(float f) {
    union { float f; unsigned u; } v; v.f = f;
    unsigned r = (v.u + 0x7FFFu + ((v.u >> 16) & 1u)) >> 16;
    return (ushort)r;
}
__device__ inline float bf2f(ushort u) {
    union { unsigned u; float f; } v; v.u = ((unsigned)u) << 16;
    return v.f;
}

// ---------------------------------------------------------------------------
// fp32 -> bf16 cast
// ---------------------------------------------------------------------------
__global__ __launch_bounds__(256) void cast_kernel(
    const float* __restrict__ src, ushort* __restrict__ dst, int n4)
{
    const int stride = gridDim.x * 256;
    for (int i = blockIdx.x * 256 + threadIdx.x; i < n4; i += stride) {
        float4 v = *(const float4*)(src + (size_t)i * 4);
        ushort4 o;
        o.x = f2bf(v.x); o.y = f2bf(v.y); o.z = f2bf(v.z); o.w = f2bf(v.w);
        *(ushort4*)(dst + (size_t)i * 4) = o;
    }
}

// ---------------------------------------------------------------------------
// bf16 MFMA GEMM. 128x128 tile, BK=32, 4 waves (2x2), A+B double-buffered,
// one __syncthreads per K-step, stage(t+1) issued before compute(t).
// LDS in FRAGMENT order: chunk = 16 rows x 32 k = 1 KB, staged with per-lane
// global src (row=lane&15, k+=(lane>>4)*8) into a linear dest; the MFMA
// fragment read is then base + lane*16 B -> bank-conflict-free ds_read_b128.
// STATS=true: XCD-chunked job swizzle; writes bf16 C into the TOP HALF of
//   each d_out row slot (ushort offset cTOP, stride cCBLD) + per-(panel,row)
//   softmax partials pm/ps transposed (pm[pan*M + row]).
// STATS=false: plain mapping, fp32 C + bias at stride ldc.
// ---------------------------------------------------------------------------
template<bool STATS>
__global__ __launch_bounds__(256) void gemm2(
    const ushort* __restrict__ A, const ushort* __restrict__ Wb,
    const float* __restrict__ bias,
    float* __restrict__ Cf, ushort* __restrict__ Cb,
    float* __restrict__ pm, float* __restrict__ ps,
    int M, int N, int K, int ldc)
{
    __shared__ ushort As[2][128 * 32];   // 8 chunks x 512 ushorts, frag order
    __shared__ ushort Bs[2][128 * 32];
    __shared__ float sm_m[2][128];
    __shared__ float sm_s[2][128];

    const int tid  = threadIdx.x;
    const int lane = tid & 63;
    const int wv   = tid >> 6;
    const int wm   = wv >> 1;
    const int wn   = wv & 1;

    int bm, bn, pan = 0;
    if constexpr (STATS) {
        // XCD-chunked swizzle: nwg = 8*cPAN, 8 | nwg
        const int wg  = blockIdx.y * gridDim.x + blockIdx.x;
        const int nwg = gridDim.x * gridDim.y;
        const int j   = (wg & 7) * (nwg >> 3) + (wg >> 3);
        pan = j >> 3;                  // gridDim.x == 8 row-blocks
        bm  = (j & 7) * 128;
        bn  = pan * 128;
    } else {
        bm = blockIdx.x * 128;
        bn = blockIdx.y * 128;
    }

    const int rA = lane & 15;          // fragment row within 16-row chunk
    const int kA = (lane >> 4) * 8;    // fragment k offset (bf16 elems)
    const int nt = K >> 5;

    floatx4 acc[4][4] = {};

    auto stage = [&](int bidx, int t) {
        const int k0 = t * 32;
        #pragma unroll
        for (int c = 0; c < 2; ++c) {
            const int chunk = wv * 2 + c;          // 0..7
            int ga = bm + chunk * 16 + rA; if (ga >= M) ga = M - 1;
            __builtin_amdgcn_global_load_lds(
                (const __attribute__((address_space(1))) void*)(A + (size_t)ga * K + k0 + kA),
                (__attribute__((address_space(3))) void*)&As[bidx][chunk * 512], 16, 0, 0);
            int gb = bn + chunk * 16 + rA; if (gb >= N) gb = N - 1;
            __builtin_amdgcn_global_load_lds(
                (const __attribute__((address_space(1))) void*)(Wb + (size_t)gb * K + k0 + kA),
                (__attribute__((address_space(3))) void*)&Bs[bidx][chunk * 512], 16, 0, 0);
        }
    };

    stage(0, 0);
    __syncthreads();

    const int fr = lane & 15;
    const int g  = lane >> 4;
    int buf = 0;

    for (int t = 0; t < nt; ++t) {
        if (t + 1 < nt) stage(buf ^ 1, t + 1);
        short8v a[4], b[4];
        #pragma unroll
        for (int mi = 0; mi < 4; ++mi)
            a[mi] = *(const short8v*)&As[buf][(wm * 4 + mi) * 512 + lane * 8];
        #pragma unroll
        for (int ni = 0; ni < 4; ++ni)
            b[ni] = *(const short8v*)&Bs[buf][(wn * 4 + ni) * 512 + lane * 8];
        #pragma unroll
        for (int mi = 0; mi < 4; ++mi)
            #pragma unroll
            for (int ni = 0; ni < 4; ++ni)
                acc[mi][ni] = __builtin_amdgcn_mfma_f32_16x16x32_bf16(
                    a[mi], b[ni], acc[mi][ni], 0, 0, 0);
        __syncthreads();
        buf ^= 1;
    }

    // ---- epilogue ----
    float bv[4]; bool val[4];
    #pragma unroll
    for (int ni = 0; ni < 4; ++ni) {
        const int colg = bn + wn * 64 + ni * 16 + fr;
        val[ni] = (colg < N);
        bv[ni] = val[ni] ? bias[colg] : 0.f;
    }
    #pragma unroll
    for (int mi = 0; mi < 4; ++mi)
        #pragma unroll
        for (int ni = 0; ni < 4; ++ni)
            #pragma unroll
            for (int r = 0; r < 4; ++r)
                acc[mi][ni][r] += bv[ni];

    if constexpr (STATS) {
        // per-(mi,r) row stats over this wave's 64 cols
        #pragma unroll
        for (int mi = 0; mi < 4; ++mi) {
            #pragma unroll
            for (int r = 0; r < 4; ++r) {
                float mx = -1e30f;
                #pragma unroll
                for (int ni = 0; ni < 4; ++ni)
                    if (val[ni]) mx = fmaxf(mx, acc[mi][ni][r]);
                #pragma unroll
                for (int sw = 1; sw < 16; sw <<= 1)
                    mx = fmaxf(mx, __shfl_xor(mx, sw));
                float sm = 0.f;
                #pragma unroll
                for (int ni = 0; ni < 4; ++ni)
                    if (val[ni]) sm += __expf(acc[mi][ni][r] - mx);
                #pragma unroll
                for (int sw = 1; sw < 16; sw <<= 1)
                    sm += __shfl_xor(sm, sw);
                if (fr == 0) {
                    const int rl = wm * 64 + mi * 16 + g * 4 + r;
                    sm_m[wn][rl] = mx;
                    sm_s[wn][rl] = sm;
                }
            }
        }
        __syncthreads();
        if (tid < 128) {
            const float m0 = sm_m[0][tid], m1 = sm_m[1][tid];
            const float s0 = sm_s[0][tid], s1 = sm_s[1][tid];
            const float mm = fmaxf(m0, m1);
            const float ss = s0 * __expf(m0 - mm) + s1 * __expf(m1 - mm);
            const int grow = bm + tid;
            if (grow < M) {
                pm[(size_t)pan * M + grow] = mm;   // transposed: contiguous
                ps[(size_t)pan * M + grow] = ss;
            }
        }
        // bf16 logits into the top half of the output row slot
        #pragma unroll
        for (int mi = 0; mi < 4; ++mi) {
            #pragma unroll
            for (int ni = 0; ni < 4; ++ni) {
                if (!val[ni]) continue;
                const int colg = bn + wn * 64 + ni * 16 + fr;
                #pragma unroll
                for (int r = 0; r < 4; ++r) {
                    const int row = bm + wm * 64 + mi * 16 + g * 4 + r;
                    Cb[(size_t)row * cCBLD + cTOP + colg] = f2bf(acc[mi][ni][r]);
                }
            }
        }
    } else {
        #pragma unroll
        for (int mi = 0; mi < 4; ++mi) {
            #pragma unroll
            for (int ni = 0; ni < 4; ++ni) {
                if (!val[ni]) continue;
                const int colg = bn + wn * 64 + ni * 16 + fr;
                #pragma unroll
                for (int r = 0; r < 4; ++r) {
                    const int row = bm + wm * 64 + mi * 16 + g * 4 + r;
                    if (row < M) Cf[(size_t)row * ldc + colg] = acc[mi][ni][r];
                }
            }
        }
    }
}

// ---------------------------------------------------------------------------
// combine partials (transposed pm/ps) -> rowadd = log(pgen) - m - log(s).
// Block = 64 rows x 4 panel-stripes; coalesced. (r9-proven.)
// ---------------------------------------------------------------------------
__global__ __launch_bounds__(256) void combine_kernel(
    const float* __restrict__ pm, const float* __restrict__ ps,
    const float* __restrict__ pgen, float* __restrict__ rowadd)
{
    const int lane = threadIdx.x & 63;
    const int wv   = threadIdx.x >> 6;    // panel stripe 0..3
    const int row  = blockIdx.x * 64 + lane;

    float m = -1e30f, s = 0.f;
    #pragma unroll 2
    for (int i = wv; i < cPAN; i += 4) {
        const float mi = pm[(size_t)i * cMQ + row];
        const float si = ps[(size_t)i * cMQ + row];
        const float nm = fmaxf(m, mi);
        s = s * __expf(m - nm) + si * __expf(mi - nm);
        m = nm;
    }
    __shared__ float rm[4][64], rs[4][64];
    rm[wv][lane] = m; rs[wv][lane] = s;
    __syncthreads();
    if (wv == 0) {
        m = rm[0][lane]; s = rs[0][lane];
        #pragma unroll
        for (int i = 1; i < 4; ++i) {
            const float m2 = rm[i][lane], s2 = rs[i][lane];
            const float nm = fmaxf(m, m2);
            s = s * __expf(m - nm) + s2 * __expf(m2 - nm);
            m = nm;
        }
        rowadd[row] = __logf(pgen[row]) - m - __logf(s);
    }
}

// ---------------------------------------------------------------------------
// Round-batched in-place expand from the row slot's TOP-half bf16 logits to
// full fp32 log-probs, + fused scatter fixup. One block (512) per row.
// Safety: round t reads bytes [100200+8192t, +8192), writes [16384t, +16384).
// Writes of rounds <= t never reach reads of rounds > t (16384(t+1) <
// 100200+8192(t+1) for all t <= 12); intra-round WAR is killed by the
// __syncthreads between load and store (compiler drains vmcnt before
// s_barrier). Tail written after the last round's barrier.
// ---------------------------------------------------------------------------
__global__ __launch_bounds__(512) void transform_reg(
    float* __restrict__ out, const float* __restrict__ rowadd,
    const int* __restrict__ ebev, const float* __restrict__ attn)
{
    const int row = blockIdx.x;
    const int b   = row / cT;
    const int tid = threadIdx.x;
    constexpr float LOGMIN = -20.72326583694641f;   // log(1e-9)

    __shared__ int   pos[cS];
    __shared__ float add[cS];
    for (int s = tid; s < cS; s += 512) {
        pos[s] = ebev[b * cS + s];
        add[s] = attn[(size_t)row * cS + s];
    }

    const float a = rowadd[row];
    const ushort* rowu = (const ushort*)out + (size_t)row * cCBLD + cTOP;
    float* rowf = out + (size_t)row * cVEXT;

    #pragma unroll 1
    for (int t = 0; t < 13; ++t) {
        const int cidx = t * 512 + tid;        // chunk of 8 bf16
        const bool v = cidx < cV / 8;          // 6250 chunks
        ushort4 lo = {}, hi = {};
        if (v) {
            lo = *(const ushort4*)(rowu + (size_t)cidx * 8);
            hi = *(const ushort4*)(rowu + (size_t)cidx * 8 + 4);
        }
        __syncthreads();   // all reads of this round land before any store
        if (v) {
            const int j = cidx * 8;
            float2 o;
            o.x = fmaxf(bf2f(lo.x) + a, LOGMIN);
            o.y = fmaxf(bf2f(lo.y) + a, LOGMIN);
            *(float2*)(rowf + j) = o;
            o.x = fmaxf(bf2f(lo.z) + a, LOGMIN);
            o.y = fmaxf(bf2f(lo.w) + a, LOGMIN);
            *(float2*)(rowf + j + 2) = o;
            o.x = fmaxf(bf2f(hi.x) + a, LOGMIN);
            o.y = fmaxf(bf2f(hi.y) + a, LOGMIN);
            *(float2*)(rowf + j + 4) = o;
            o.x = fmaxf(bf2f(hi.z) + a, LOGMIN);
            o.y = fmaxf(bf2f(hi.w) + a, LOGMIN);
            *(float2*)(rowf + j + 6) = o;
        }
    }
    // LOGMIN tail [cV, cVEXT): after the last round's barrier, so the last
    // round's reads (which extend to the row end) have already completed.
    if (tid < (cVEXT - cV) / 2) {
        float2 z; z.x = LOGMIN; z.y = LOGMIN;
        *(float2*)(rowf + cV + 2 * tid) = z;
    }
    __syncthreads();

    // scatter fixup
    for (int s = tid; s < cS; s += 512) {
        const int p = pos[s];
        bool leader = true;
        for (int s2 = 0; s2 < s; ++s2)
            if (pos[s2] == p) { leader = false; break; }
        if (!leader) continue;
        float sum = add[s];
        for (int s2 = s + 1; s2 < cS; ++s2)
            if (pos[s2] == p) sum += add[s2];
        const float base = __expf(rowf[p]);   // clamped; error << threshold
        rowf[p] = __logf(fmaxf(base + sum, 1e-9f));
    }
}

// ---------------------------------------------------------------------------
// p_gen = sigmoid(x . pgen_w + pgen_b)
// ---------------------------------------------------------------------------
__global__ __launch_bounds__(64) void pgen_kernel(
    const float* __restrict__ x, const float* __restrict__ w,
    const float* __restrict__ b, float* __restrict__ pgen)
{
    const int row = blockIdx.x;
    const int lane = threadIdx.x;
    const float* xr = x + (size_t)row * cD;
    float s = 0.f;
    for (int i = lane; i < cD; i += 64) s += xr[i] * w[i];
    #pragma unroll
    for (int off = 32; off; off >>= 1) s += __shfl_down(s, off);
    if (lane == 0) pgen[row] = 1.f / (1.f + __expf(-(s + b[0])));
}

// ---------------------------------------------------------------------------
// attention distribution (scaled by 1-pgen)
// ---------------------------------------------------------------------------
__global__ __launch_bounds__(256) void attn_kernel(
    const float* __restrict__ q, const float* __restrict__ k,
    const int* __restrict__ src_mask, const float* __restrict__ pgen,
    float* __restrict__ attn)
{
    constexpr float scale = 0.04419417382415922f;  // 1/sqrt(512)
    const int row = blockIdx.x;      // b*T + t
    const int b = row / cT;
    const int tid = threadIdx.x;

    __shared__ __align__(16) float qs[cD];
    __shared__ float sc[cS];
    __shared__ float red[4];

    for (int i = tid; i < cD; i += 256) qs[i] = q[(size_t)row * cD + i];
    __syncthreads();

    for (int s = tid; s < cS; s += 256) {
        const float* kr = k + ((size_t)b * cS + s) * cD;
        float dot = 0.f;
        #pragma unroll 4
        for (int i = 0; i < cD; i += 4) {
            float4 kv = *(const float4*)(kr + i);
            float4 qv = *(const float4*)(qs + i);
            dot += qv.x * kv.x + qv.y * kv.y + qv.z * kv.z + qv.w * kv.w;
        }
        float v = dot * scale;
        if (src_mask[b * cS + s] == 0) v = -1e9f;
        sc[s] = v;
    }
    __syncthreads();

    float m = -3.4e38f;
    for (int s = tid; s < cS; s += 256) m = fmaxf(m, sc[s]);
    #pragma unroll
    for (int off = 32; off; off >>= 1) m = fmaxf(m, __shfl_down(m, off));
    if ((tid & 63) == 0) red[tid >> 6] = m;
    __syncthreads();
    m = fmaxf(fmaxf(red[0], red[1]), fmaxf(red[2], red[3]));
    __syncthreads();

    float sum = 0.f;
    for (int s = tid; s < cS; s += 256) {
        float e = __expf(sc[s] - m);
        sc[s] = e;
        sum += e;
    }
    #pragma unroll
    for (int off = 32; off; off >>= 1) sum += __shfl_down(sum, off);
    if ((tid & 63) == 0) red[tid >> 6] = sum;
    __syncthreads();
    sum = red[0] + red[1] + red[2] + red[3];

    const float w = (1.f - pgen[row]) / sum;
    for (int s = tid; s < cS; s += 256)
        attn[(size_t)row * cS + s] = sc[s] * w;
}

extern "C" void kernel_launch(void* const* d_in, const int* in_sizes, int n_in,
                              void* d_out, int out_size, void* d_ws, size_t ws_size,
                              hipStream_t stream)
{
    const float* x      = (const float*)d_in[0];   // (B,T,D)
    const float* enc    = (const float*)d_in[1];   // (B,S,D)
    const int*   mask   = (const int*)d_in[2];     // (B,1,S)
    const int*   ebev   = (const int*)d_in[3];     // (B,S)
    const float* fc_w   = (const float*)d_in[5];   // (V,D)
    const float* fc_b   = (const float*)d_in[6];   // (V,)
    const float* pgen_w = (const float*)d_in[7];   // (1,D)
    const float* pgen_b = (const float*)d_in[8];   // (1,)
    const float* wq     = (const float*)d_in[9];   // (D,D)
    const float* bq     = (const float*)d_in[10];  // (D,)
    const float* wk     = (const float*)d_in[11];  // (D,D)
    const float* bk     = (const float*)d_in[12];  // (D,)
    float* out = (float*)d_out;

    // workspace layout (~65 MB; proven to fit in prior rounds)
    float* ws     = (float*)d_ws;
    float* q      = ws;                                   // 1024*512
    float* kbuf   = q + (size_t)cB * cT * cD;             // 1600*512
    float* pgen   = kbuf + (size_t)cB * cS * cD;          // 1024
    float* attn   = pgen + cB * cT;                       // 1024*400
    float* pm     = attn + (size_t)cB * cT * cS;          // 391*1024 (transposed)
    float* ps     = pm + (size_t)cPAN * cMQ;              // 391*1024
    float* rowadd = ps + (size_t)cPAN * cMQ;              // 1024
    ushort* xb    = (ushort*)(rowadd + cMQ);
    ushort* encb  = xb + (size_t)cB * cT * cD;
    ushort* wqb   = encb + (size_t)cB * cS * cD;
    ushort* wkb   = wqb + (size_t)cD * cD;
    ushort* wb    = wkb + (size_t)cD * cD;                // V*D bf16 (51 MB)

    const dim3 blk(256);
    const int MQ = cMQ;        // 1024
    const int MK = cB * cS;    // 1600

    // casts
    cast_kernel<<<dim3(512), blk, 0, stream>>>(x, xb, (cB * cT * cD) / 4);
    cast_kernel<<<dim3(512), blk, 0, stream>>>(enc, encb, (cB * cS * cD) / 4);
    cast_kernel<<<dim3(256), blk, 0, stream>>>(wq, wqb, (cD * cD) / 4);
    cast_kernel<<<dim3(256), blk, 0, stream>>>(wk, wkb, (cD * cD) / 4);
    cast_kernel<<<dim3(2048), blk, 0, stream>>>(fc_w, wb, (cV * cD) / 4);

    // projections (bf16 MFMA, fp32 out)
    gemm2<false><<<dim3(MQ / 128, cD / 128), blk, 0, stream>>>(
        xb, wqb, bq, q, nullptr, nullptr, nullptr, MQ, cD, cD, cD);
    gemm2<false><<<dim3((MK + 127) / 128, cD / 128), blk, 0, stream>>>(
        encb, wkb, bk, kbuf, nullptr, nullptr, nullptr, MK, cD, cD, cD);
    pgen_kernel<<<dim3(MQ), dim3(64), 0, stream>>>(x, pgen_w, pgen_b, pgen);

    // attention distribution
    attn_kernel<<<dim3(MQ), blk, 0, stream>>>(q, kbuf, mask, pgen, attn);

    // big logits GEMM: bf16 logits into row-slot top half + softmax partials
    gemm2<true><<<dim3(8, cPAN), blk, 0, stream>>>(
        xb, wb, fc_b, nullptr, (ushort*)out, pm, ps, MQ, cV, cD, 0);

    // combine partials -> rowadd
    combine_kernel<<<dim3(MQ / 64), blk, 0, stream>>>(pm, ps, pgen, rowadd);

    // round-batched in-place expand + fused scatter fixup
    transform_reg<<<dim3(MQ), dim3(512), 0, stream>>>(out, rowadd, ebev, attn);
}

// Round 11
// 423.264 us; speedup vs baseline: 1.4217x; 1.0478x over previous
//
#include <hip/hip_runtime.h>
#include <hip/hip_bf16.h>
#include <math.h>

// Problem constants
constexpr int cB = 4, cT = 256, cS = 400, cD = 512, cV = 50000, cNX = 50;
constexpr int cVEXT = cV + cNX;           // 50050
constexpr int cPAN2 = (cV + 255) / 256;   // 196 col panels (256-wide) of big GEMM
constexpr int cCBLD = cVEXT * 2;          // ushort stride of one fp32 out row
constexpr int cTOP  = 50100;              // ushort offset of bf16 logits in-slot
constexpr int cMQ   = cB * cT;            // 1024

typedef __attribute__((ext_vector_type(8))) short short8v;   // 8 bf16
typedef __attribute__((ext_vector_type(4))) float floatx4;

__device__ inline ushort f2bf(float f) {
    union { float f; unsigned u; } v; v.f = f;
    unsigned r = (v.u + 0x7FFFu + ((v.u >> 16) & 1u)) >> 16;
    return (ushort)r;
}
__device__ inline float bf2f(ushort u) {
    union { unsigned u; float f; } v; v.u = ((unsigned)u) << 16;
    return v.f;
}

// ---------------------------------------------------------------------------
// fp32 -> bf16 cast
// ---------------------------------------------------------------------------
__global__ __launch_bounds__(256) void cast_kernel(
    const float* __restrict__ src, ushort* __restrict__ dst, int n4)
{
    const int stride = gridDim.x * 256;
    for (int i = blockIdx.x * 256 + threadIdx.x; i < n4; i += stride) {
        float4 v = *(const float4*)(src + (size_t)i * 4);
        ushort4 o;
        o.x = f2bf(v.x); o.y = f2bf(v.y); o.z = f2bf(v.z); o.w = f2bf(v.w);
        *(ushort4*)(dst + (size_t)i * 4) = o;
    }
}

// ---------------------------------------------------------------------------
// Small bf16 MFMA GEMM (projections): 128x128 tile, BK=32, 4 waves, frag-order
// LDS (r10-verified, 0 bank conflicts), fp32 C + bias. Plain block mapping.
// ---------------------------------------------------------------------------
__global__ __launch_bounds__(256) void gemm_proj(
    const ushort* __restrict__ A, const ushort* __restrict__ Wb,
    const float* __restrict__ bias, float* __restrict__ Cf,
    int M, int N, int K, int ldc)
{
    __shared__ ushort As[2][128 * 32];
    __shared__ ushort Bs[2][128 * 32];

    const int tid  = threadIdx.x;
    const int lane = tid & 63;
    const int wv   = tid >> 6;
    const int wm   = wv >> 1;
    const int wn   = wv & 1;
    const int bm   = blockIdx.x * 128;
    const int bn   = blockIdx.y * 128;

    const int rA = lane & 15;
    const int kA = (lane >> 4) * 8;
    const int nt = K >> 5;

    floatx4 acc[4][4] = {};

    auto stage = [&](int bidx, int t) {
        const int k0 = t * 32;
        #pragma unroll
        for (int c = 0; c < 2; ++c) {
            const int chunk = wv * 2 + c;
            int ga = bm + chunk * 16 + rA; if (ga >= M) ga = M - 1;
            __builtin_amdgcn_global_load_lds(
                (const __attribute__((address_space(1))) void*)(A + (size_t)ga * K + k0 + kA),
                (__attribute__((address_space(3))) void*)&As[bidx][chunk * 512], 16, 0, 0);
            int gb = bn + chunk * 16 + rA; if (gb >= N) gb = N - 1;
            __builtin_amdgcn_global_load_lds(
                (const __attribute__((address_space(1))) void*)(Wb + (size_t)gb * K + k0 + kA),
                (__attribute__((address_space(3))) void*)&Bs[bidx][chunk * 512], 16, 0, 0);
        }
    };

    stage(0, 0);
    __syncthreads();

    int buf = 0;
    for (int t = 0; t < nt; ++t) {
        if (t + 1 < nt) stage(buf ^ 1, t + 1);
        short8v a[4], b[4];
        #pragma unroll
        for (int mi = 0; mi < 4; ++mi)
            a[mi] = *(const short8v*)&As[buf][(wm * 4 + mi) * 512 + lane * 8];
        #pragma unroll
        for (int ni = 0; ni < 4; ++ni)
            b[ni] = *(const short8v*)&Bs[buf][(wn * 4 + ni) * 512 + lane * 8];
        #pragma unroll
        for (int mi = 0; mi < 4; ++mi)
            #pragma unroll
            for (int ni = 0; ni < 4; ++ni)
                acc[mi][ni] = __builtin_amdgcn_mfma_f32_16x16x32_bf16(
                    a[mi], b[ni], acc[mi][ni], 0, 0, 0);
        __syncthreads();
        buf ^= 1;
    }

    const int fr = lane & 15;
    const int g  = lane >> 4;
    #pragma unroll
    for (int mi = 0; mi < 4; ++mi) {
        #pragma unroll
        for (int ni = 0; ni < 4; ++ni) {
            const int colg = bn + wn * 64 + ni * 16 + fr;
            if (colg >= N) continue;
            const float bv = bias[colg];
            #pragma unroll
            for (int r = 0; r < 4; ++r) {
                const int row = bm + wm * 64 + mi * 16 + g * 4 + r;
                if (row < M) Cf[(size_t)row * ldc + colg] = acc[mi][ni][r] + bv;
            }
        }
    }
}

// ---------------------------------------------------------------------------
// Big logits GEMM: 128x256 tile, BK=32, 512 thr = 8 waves (2m x 4n).
// LDS 48KB -> 3 blocks/CU = 24 waves/CU (latency hiding). Frag-order LDS
// (0-conflict, r10-verified). XCD-chunked swizzle (nwg=1568, 8|nwg).
// Writes bf16 logits into TOP half of each d_out row slot + per-(panel,row)
// softmax partials pm/ps transposed (pm[pan*cMQ + row]).
// M=1024, K=512, N=cV fixed.
// ---------------------------------------------------------------------------
__global__ __launch_bounds__(512) void gemm_big(
    const ushort* __restrict__ A, const ushort* __restrict__ Wb,
    const float* __restrict__ bias, ushort* __restrict__ Cb,
    float* __restrict__ pm, float* __restrict__ ps)
{
    __shared__ ushort As[2][8 * 512];     // 8 chunks (128 rows x 32 k)
    __shared__ ushort Bs[2][16 * 512];    // 16 chunks (256 cols x 32 k)
    __shared__ float sm_m[4][128];
    __shared__ float sm_s[4][128];

    const int tid  = threadIdx.x;
    const int lane = tid & 63;
    const int wv   = tid >> 6;     // 0..7
    const int wm   = wv >> 2;      // 0..1 row half
    const int wn   = wv & 3;       // 0..3 col quarter

    // XCD-chunked swizzle over (panel, rowblock); grid (8, 196)
    const int wg  = blockIdx.y * gridDim.x + blockIdx.x;
    const int nwg = gridDim.x * gridDim.y;          // 1568, 8 | nwg
    const int j   = (wg & 7) * (nwg >> 3) + (wg >> 3);
    const int pan = j >> 3;
    const int bm  = (j & 7) * 128;
    const int bn  = pan * 256;

    const int rA = lane & 15;
    const int kA = (lane >> 4) * 8;

    floatx4 acc[4][4] = {};

    auto stage = [&](int bidx, int t) {
        const int k0 = t * 32;
        {   // A: chunk wv
            const int ga = bm + wv * 16 + rA;
            __builtin_amdgcn_global_load_lds(
                (const __attribute__((address_space(1))) void*)(A + (size_t)ga * cD + k0 + kA),
                (__attribute__((address_space(3))) void*)&As[bidx][wv * 512], 16, 0, 0);
        }
        #pragma unroll
        for (int c = 0; c < 2; ++c) {   // B: chunks 2wv, 2wv+1
            const int chunk = wv * 2 + c;
            int gb = bn + chunk * 16 + rA; if (gb >= cV) gb = cV - 1;
            __builtin_amdgcn_global_load_lds(
                (const __attribute__((address_space(1))) void*)(Wb + (size_t)gb * cD + k0 + kA),
                (__attribute__((address_space(3))) void*)&Bs[bidx][chunk * 512], 16, 0, 0);
        }
    };

    stage(0, 0);
    __syncthreads();

    int buf = 0;
    #pragma unroll 1
    for (int t = 0; t < 16; ++t) {
        if (t + 1 < 16) stage(buf ^ 1, t + 1);
        short8v a[4], b[4];
        #pragma unroll
        for (int mi = 0; mi < 4; ++mi)
            a[mi] = *(const short8v*)&As[buf][(wm * 4 + mi) * 512 + lane * 8];
        #pragma unroll
        for (int ni = 0; ni < 4; ++ni)
            b[ni] = *(const short8v*)&Bs[buf][(wn * 4 + ni) * 512 + lane * 8];
        #pragma unroll
        for (int mi = 0; mi < 4; ++mi)
            #pragma unroll
            for (int ni = 0; ni < 4; ++ni)
                acc[mi][ni] = __builtin_amdgcn_mfma_f32_16x16x32_bf16(
                    a[mi], b[ni], acc[mi][ni], 0, 0, 0);
        __syncthreads();
        buf ^= 1;
    }

    // ---- epilogue: bias, per-row stats over 256 cols, bf16 store ----
    const int fr = lane & 15;
    const int g  = lane >> 4;

    float bv[4]; bool val[4];
    #pragma unroll
    for (int ni = 0; ni < 4; ++ni) {
        const int colg = bn + wn * 64 + ni * 16 + fr;
        val[ni] = (colg < cV);
        bv[ni] = val[ni] ? bias[colg] : 0.f;
    }
    #pragma unroll
    for (int mi = 0; mi < 4; ++mi)
        #pragma unroll
        for (int ni = 0; ni < 4; ++ni)
            #pragma unroll
            for (int r = 0; r < 4; ++r)
                acc[mi][ni][r] += bv[ni];

    #pragma unroll
    for (int mi = 0; mi < 4; ++mi) {
        #pragma unroll
        for (int r = 0; r < 4; ++r) {
            float mx = -1e30f;
            #pragma unroll
            for (int ni = 0; ni < 4; ++ni)
                if (val[ni]) mx = fmaxf(mx, acc[mi][ni][r]);
            #pragma unroll
            for (int sw = 1; sw < 16; sw <<= 1)
                mx = fmaxf(mx, __shfl_xor(mx, sw));
            float sm = 0.f;
            #pragma unroll
            for (int ni = 0; ni < 4; ++ni)
                if (val[ni]) sm += __expf(acc[mi][ni][r] - mx);
            #pragma unroll
            for (int sw = 1; sw < 16; sw <<= 1)
                sm += __shfl_xor(sm, sw);
            if (fr == 0) {
                const int rl = wm * 64 + mi * 16 + g * 4 + r;
                sm_m[wn][rl] = mx;
                sm_s[wn][rl] = sm;
            }
        }
    }
    __syncthreads();
    if (tid < 128) {
        float m = sm_m[0][tid], s = sm_s[0][tid];
        #pragma unroll
        for (int i = 1; i < 4; ++i) {
            const float m2 = sm_m[i][tid], s2 = sm_s[i][tid];
            const float nm = fmaxf(m, m2);
            s = s * __expf(m - nm) + s2 * __expf(m2 - nm);
            m = nm;
        }
        const int grow = bm + tid;
        pm[(size_t)pan * cMQ + grow] = m;
        ps[(size_t)pan * cMQ + grow] = s;
    }

    // bf16 logits into top half of output row slot
    #pragma unroll
    for (int mi = 0; mi < 4; ++mi) {
        #pragma unroll
        for (int ni = 0; ni < 4; ++ni) {
            if (!val[ni]) continue;
            const int colg = bn + wn * 64 + ni * 16 + fr;
            #pragma unroll
            for (int r = 0; r < 4; ++r) {
                const int row = bm + wm * 64 + mi * 16 + g * 4 + r;
                Cb[(size_t)row * cCBLD + cTOP + colg] = f2bf(acc[mi][ni][r]);
            }
        }
    }
}

// ---------------------------------------------------------------------------
// combine partials (transposed pm/ps) -> rowadd = log(pgen) - m - log(s).
// Block = 64 rows x 4 panel-stripes; coalesced.
// ---------------------------------------------------------------------------
__global__ __launch_bounds__(256) void combine_kernel(
    const float* __restrict__ pm, const float* __restrict__ ps,
    const float* __restrict__ pgen, float* __restrict__ rowadd)
{
    const int lane = threadIdx.x & 63;
    const int wv   = threadIdx.x >> 6;    // panel stripe 0..3
    const int row  = blockIdx.x * 64 + lane;

    float m = -1e30f, s = 0.f;
    #pragma unroll 2
    for (int i = wv; i < cPAN2; i += 4) {
        const float mi = pm[(size_t)i * cMQ + row];
        const float si = ps[(size_t)i * cMQ + row];
        const float nm = fmaxf(m, mi);
        s = s * __expf(m - nm) + si * __expf(mi - nm);
        m = nm;
    }
    __shared__ float rm[4][64], rs[4][64];
    rm[wv][lane] = m; rs[wv][lane] = s;
    __syncthreads();
    if (wv == 0) {
        m = rm[0][lane]; s = rs[0][lane];
        #pragma unroll
        for (int i = 1; i < 4; ++i) {
            const float m2 = rm[i][lane], s2 = rs[i][lane];
            const float nm = fmaxf(m, m2);
            s = s * __expf(m - nm) + s2 * __expf(m2 - nm);
            m = nm;
        }
        rowadd[row] = __logf(pgen[row]) - m - __logf(s);
    }
}

// ---------------------------------------------------------------------------
// Register-phase in-place transform + fused scatter fixup. One block/row.
// Phase A: each of 512 threads loads its 13 chunks (8 bf16 each, 2x ushort4
// 8B-aligned loads) into registers -- NO barriers, all loads concurrent.
// Barrier (drains vmcnt: every read complete). Phase B: write all fp32.
// Block owns the row -> no cross-block hazard.
// ---------------------------------------------------------------------------
__global__ __launch_bounds__(512) void transform_reg(
    float* __restrict__ out, const float* __restrict__ rowadd,
    const int* __restrict__ ebev, const float* __restrict__ attn)
{
    const int row = blockIdx.x;
    const int b   = row / cT;
    const int tid = threadIdx.x;
    constexpr float LOGMIN = -20.72326583694641f;   // log(1e-9)
    constexpr int NCHUNK = cV / 8;                  // 6250

    __shared__ int   pos[cS];
    __shared__ float add[cS];
    for (int s = tid; s < cS; s += 512) {
        pos[s] = ebev[b * cS + s];
        add[s] = attn[(size_t)row * cS + s];
    }

    const float a = rowadd[row];
    const ushort* rowu = (const ushort*)out + (size_t)row * cCBLD + cTOP;
    float* rowf = out + (size_t)row * cVEXT;

    ushort4 lo[13], hi[13];
    #pragma unroll
    for (int t = 0; t < 13; ++t) {
        const int cidx = t * 512 + tid;
        if (cidx < NCHUNK) {
            lo[t] = *(const ushort4*)(rowu + (size_t)cidx * 8);
            hi[t] = *(const ushort4*)(rowu + (size_t)cidx * 8 + 4);
        }
    }
    __syncthreads();   // vmcnt drained: all reads of the row are complete

    #pragma unroll
    for (int t = 0; t < 13; ++t) {
        const int cidx = t * 512 + tid;
        if (cidx < NCHUNK) {
            const int jb = cidx * 8;
            float2 o;
            o.x = fmaxf(bf2f(lo[t].x) + a, LOGMIN);
            o.y = fmaxf(bf2f(lo[t].y) + a, LOGMIN);
            *(float2*)(rowf + jb) = o;
            o.x = fmaxf(bf2f(lo[t].z) + a, LOGMIN);
            o.y = fmaxf(bf2f(lo[t].w) + a, LOGMIN);
            *(float2*)(rowf + jb + 2) = o;
            o.x = fmaxf(bf2f(hi[t].x) + a, LOGMIN);
            o.y = fmaxf(bf2f(hi[t].y) + a, LOGMIN);
            *(float2*)(rowf + jb + 4) = o;
            o.x = fmaxf(bf2f(hi[t].z) + a, LOGMIN);
            o.y = fmaxf(bf2f(hi[t].w) + a, LOGMIN);
            *(float2*)(rowf + jb + 6) = o;
        }
    }
    if (tid < (cVEXT - cV) / 2) {   // LOGMIN tail [50000, 50050)
        float2 z; z.x = LOGMIN; z.y = LOGMIN;
        *(float2*)(rowf + cV + 2 * tid) = z;
    }
    __syncthreads();

    // scatter fixup
    for (int s = tid; s < cS; s += 512) {
        const int p = pos[s];
        bool leader = true;
        for (int s2 = 0; s2 < s; ++s2)
            if (pos[s2] == p) { leader = false; break; }
        if (!leader) continue;
        float sum = add[s];
        for (int s2 = s + 1; s2 < cS; ++s2)
            if (pos[s2] == p) sum += add[s2];
        const float base = __expf(rowf[p]);   // clamped; error << threshold
        rowf[p] = __logf(fmaxf(base + sum, 1e-9f));
    }
}

// ---------------------------------------------------------------------------
// p_gen = sigmoid(x . pgen_w + pgen_b)
// ---------------------------------------------------------------------------
__global__ __launch_bounds__(64) void pgen_kernel(
    const float* __restrict__ x, const float* __restrict__ w,
    const float* __restrict__ b, float* __restrict__ pgen)
{
    const int row = blockIdx.x;
    const int lane = threadIdx.x;
    const float* xr = x + (size_t)row * cD;
    float s = 0.f;
    for (int i = lane; i < cD; i += 64) s += xr[i] * w[i];
    #pragma unroll
    for (int off = 32; off; off >>= 1) s += __shfl_down(s, off);
    if (lane == 0) pgen[row] = 1.f / (1.f + __expf(-(s + b[0])));
}

// ---------------------------------------------------------------------------
// attention distribution (scaled by 1-pgen)
// ---------------------------------------------------------------------------
__global__ __launch_bounds__(256) void attn_kernel(
    const float* __restrict__ q, const float* __restrict__ k,
    const int* __restrict__ src_mask, const float* __restrict__ pgen,
    float* __restrict__ attn)
{
    constexpr float scale = 0.04419417382415922f;  // 1/sqrt(512)
    const int row = blockIdx.x;      // b*T + t
    const int b = row / cT;
    const int tid = threadIdx.x;

    __shared__ __align__(16) float qs[cD];
    __shared__ float sc[cS];
    __shared__ float red[4];

    for (int i = tid; i < cD; i += 256) qs[i] = q[(size_t)row * cD + i];
    __syncthreads();

    for (int s = tid; s < cS; s += 256) {
        const float* kr = k + ((size_t)b * cS + s) * cD;
        float dot = 0.f;
        #pragma unroll 4
        for (int i = 0; i < cD; i += 4) {
            float4 kv = *(const float4*)(kr + i);
            float4 qv = *(const float4*)(qs + i);
            dot += qv.x * kv.x + qv.y * kv.y + qv.z * kv.z + qv.w * kv.w;
        }
        float v = dot * scale;
        if (src_mask[b * cS + s] == 0) v = -1e9f;
        sc[s] = v;
    }
    __syncthreads();

    float m = -3.4e38f;
    for (int s = tid; s < cS; s += 256) m = fmaxf(m, sc[s]);
    #pragma unroll
    for (int off = 32; off; off >>= 1) m = fmaxf(m, __shfl_down(m, off));
    if ((tid & 63) == 0) red[tid >> 6] = m;
    __syncthreads();
    m = fmaxf(fmaxf(red[0], red[1]), fmaxf(red[2], red[3]));
    __syncthreads();

    float sum = 0.f;
    for (int s = tid; s < cS; s += 256) {
        float e = __expf(sc[s] - m);
        sc[s] = e;
        sum += e;
    }
    #pragma unroll
    for (int off = 32; off; off >>= 1) sum += __shfl_down(sum, off);
    if ((tid & 63) == 0) red[tid >> 6] = sum;
    __syncthreads();
    sum = red[0] + red[1] + red[2] + red[3];

    const float w = (1.f - pgen[row]) / sum;
    for (int s = tid; s < cS; s += 256)
        attn[(size_t)row * cS + s] = sc[s] * w;
}

extern "C" void kernel_launch(void* const* d_in, const int* in_sizes, int n_in,
                              void* d_out, int out_size, void* d_ws, size_t ws_size,
                              hipStream_t stream)
{
    const float* x      = (const float*)d_in[0];   // (B,T,D)
    const float* enc    = (const float*)d_in[1];   // (B,S,D)
    const int*   mask   = (const int*)d_in[2];     // (B,1,S)
    const int*   ebev   = (const int*)d_in[3];     // (B,S)
    const float* fc_w   = (const float*)d_in[5];   // (V,D)
    const float* fc_b   = (const float*)d_in[6];   // (V,)
    const float* pgen_w = (const float*)d_in[7];   // (1,D)
    const float* pgen_b = (const float*)d_in[8];   // (1,)
    const float* wq     = (const float*)d_in[9];   // (D,D)
    const float* bq     = (const float*)d_in[10];  // (D,)
    const float* wk     = (const float*)d_in[11];  // (D,D)
    const float* bk     = (const float*)d_in[12];  // (D,)
    float* out = (float*)d_out;

    // workspace layout (~65 MB; proven to fit)
    float* ws     = (float*)d_ws;
    float* q      = ws;                                   // 1024*512
    float* kbuf   = q + (size_t)cB * cT * cD;             // 1600*512
    float* pgen   = kbuf + (size_t)cB * cS * cD;          // 1024
    float* attn   = pgen + cB * cT;                       // 1024*400
    float* pm     = attn + (size_t)cB * cT * cS;          // 196*1024 (transposed)
    float* ps     = pm + (size_t)cPAN2 * cMQ;             // 196*1024
    float* rowadd = ps + (size_t)cPAN2 * cMQ;             // 1024
    ushort* xb    = (ushort*)(rowadd + cMQ);
    ushort* encb  = xb + (size_t)cB * cT * cD;
    ushort* wqb   = encb + (size_t)cB * cS * cD;
    ushort* wkb   = wqb + (size_t)cD * cD;
    ushort* wb    = wkb + (size_t)cD * cD;                // V*D bf16 (51 MB)

    const dim3 blk(256);
    const int MQ = cMQ;        // 1024
    const int MK = cB * cS;    // 1600

    // casts
    cast_kernel<<<dim3(512), blk, 0, stream>>>(x, xb, (cB * cT * cD) / 4);
    cast_kernel<<<dim3(512), blk, 0, stream>>>(enc, encb, (cB * cS * cD) / 4);
    cast_kernel<<<dim3(256), blk, 0, stream>>>(wq, wqb, (cD * cD) / 4);
    cast_kernel<<<dim3(256), blk, 0, stream>>>(wk, wkb, (cD * cD) / 4);
    cast_kernel<<<dim3(2048), blk, 0, stream>>>(fc_w, wb, (cV * cD) / 4);

    // projections (bf16 MFMA, fp32 out)
    gemm_proj<<<dim3(MQ / 128, cD / 128), blk, 0, stream>>>(
        xb, wqb, bq, q, MQ, cD, cD, cD);
    gemm_proj<<<dim3((MK + 127) / 128, cD / 128), blk, 0, stream>>>(
        encb, wkb, bk, kbuf, MK, cD, cD, cD);
    pgen_kernel<<<dim3(MQ), dim3(64), 0, stream>>>(x, pgen_w, pgen_b, pgen);

    // attention distribution
    attn_kernel<<<dim3(MQ), blk, 0, stream>>>(q, kbuf, mask, pgen, attn);

    // big logits GEMM: bf16 logits into row-slot top half + softmax partials
    gemm_big<<<dim3(8, cPAN2), dim3(512), 0, stream>>>(
        xb, wb, fc_b, (ushort*)out, pm, ps);

    // combine partials -> rowadd
    combine_kernel<<<dim3(MQ / 64), blk, 0, stream>>>(pm, ps, pgen, rowadd);

    // register-phase in-place expand + fused scatter fixup
    transform_reg<<<dim3(MQ), dim3(512), 0, stream>>>(out, rowadd, ebev, attn);
}